// Round 1
// baseline (449.612 us; speedup 1.0000x reference)
//
#include <hip/hip_runtime.h>
#include <hip/hip_bf16.h>
#include <cstdint>

#define B_ 4
#define S_ 2048
#define E_ 1024
#define H_ 16
#define HD_ 64
#define EPS_ 1.1920928955078125e-07f

typedef __attribute__((ext_vector_type(8))) short shortx8;
typedef __attribute__((ext_vector_type(4))) float floatx4;

// ---------------------------------------------------------------------------
// Kernel 1: fused RMSNorm + RoPE for q and k, cast to bf16, transpose to
// [B,H,S,HD]. One wave (64 lanes) per head-vector (HD=64).
// ---------------------------------------------------------------------------
__global__ __launch_bounds__(256) void qk_prep(
    const float* __restrict__ q, const float* __restrict__ k,
    const float* __restrict__ qw, const float* __restrict__ kw,
    __hip_bfloat16* __restrict__ qh, __hip_bfloat16* __restrict__ kh)
{
    const int wid  = (blockIdx.x * 256 + threadIdx.x) >> 6;  // global wave id
    const int lane = threadIdx.x & 63;
    const int BSH  = B_ * S_ * H_;

    int t = wid;
    const bool is_k = (t >= BSH);
    if (is_k) t -= BSH;
    const int h = t % H_;
    const int s = (t / H_) % S_;
    const int b = t / (H_ * S_);

    const float* __restrict__ src = is_k ? k : q;
    const float* __restrict__ w   = is_k ? kw : qw;
    __hip_bfloat16* __restrict__ dst = is_k ? kh : qh;

    const float x = src[((size_t)(b * S_ + s)) * E_ + h * HD_ + lane];

    // RMS over the 64-lane head vector
    float ss = x * x;
#pragma unroll
    for (int m = 1; m < 64; m <<= 1) ss += __shfl_xor(ss, m);
    const float r  = rsqrtf(ss * (1.0f / HD_) + EPS_);
    const float xn = x * r * w[lane];

    // RoPE: pair (2i, 2i+1), freq = s * 10000^(-i/32)
    const int   i    = lane >> 1;
    const float invf = __expf(-(float)i * (9.210340371976184f / 32.0f)); // ln(10000)/32
    const float fr   = (float)s * invf;
    const float c = cosf(fr), sn = sinf(fr);
    const float p = __shfl_xor(xn, 1);
    const float out = (lane & 1) ? (p * sn + xn * c) : (xn * c - p * sn);

    dst[((size_t)((b * H_ + h) * S_ + s)) * HD_ + lane] = __float2bfloat16(out);
}

// ---------------------------------------------------------------------------
// Kernel 2: transpose V to [B,H,HD,S] bf16 via LDS 64x64 tile.
// ---------------------------------------------------------------------------
__global__ __launch_bounds__(256) void v_trans(
    const float* __restrict__ v, __hip_bfloat16* __restrict__ vt)
{
    __shared__ __hip_bfloat16 tile[64][72];   // +8 pad: 16B-aligned rows, spread banks

    const int bh = blockIdx.y;            // b*H + h
    const int s0 = blockIdx.x * 64;
    const int b  = bh >> 4, h = bh & 15;
    const int t  = threadIdx.x;

    // Phase A: coalesced load of 64 s-rows x 64 d, write LDS transposed
    {
        const int sl = t >> 2;            // local s row 0..63
        const int d0 = (t & 3) * 16;      // 16 d per thread
        const float* __restrict__ src =
            v + ((size_t)(b * S_ + s0 + sl)) * E_ + h * HD_ + d0;
        float4 f0 = ((const float4*)src)[0];
        float4 f1 = ((const float4*)src)[1];
        float4 f2 = ((const float4*)src)[2];
        float4 f3 = ((const float4*)src)[3];
        float vals[16] = {f0.x,f0.y,f0.z,f0.w, f1.x,f1.y,f1.z,f1.w,
                          f2.x,f2.y,f2.z,f2.w, f3.x,f3.y,f3.z,f3.w};
#pragma unroll
        for (int j = 0; j < 16; ++j)
            tile[d0 + j][sl] = __float2bfloat16(vals[j]);
    }
    __syncthreads();
    // Phase B: coalesced store of 64 d-rows x 64 s
    {
        const int d  = t >> 2;
        const int sg = (t & 3) * 16;
        __hip_bfloat16* __restrict__ dst =
            vt + ((size_t)(bh * HD_ + d)) * S_ + s0 + sg;
        ((uint4*)dst)[0] = *(const uint4*)&tile[d][sg];
        ((uint4*)dst)[1] = *(const uint4*)&tile[d][sg + 8];
    }
}

// ---------------------------------------------------------------------------
// Kernel 3: proj_w fp32 -> bf16
// ---------------------------------------------------------------------------
__global__ __launch_bounds__(256) void wconv(
    const float* __restrict__ w, __hip_bfloat16* __restrict__ wb)
{
    const int i = blockIdx.x * 256 + threadIdx.x;   // 4 floats per thread
    float4 f = ((const float4*)w)[i];
    wb[4 * i + 0] = __float2bfloat16(f.x);
    wb[4 * i + 1] = __float2bfloat16(f.y);
    wb[4 * i + 2] = __float2bfloat16(f.z);
    wb[4 * i + 3] = __float2bfloat16(f.w);
}

// ---------------------------------------------------------------------------
// Kernel 4: flash attention. Block = 4 waves; each wave owns 16 Q rows.
// Q tile per block = 64 rows. K tiles of 64 iterated over S with online
// softmax. MFMA 16x16x32 bf16; layouts per m89/m91/m120 verified mappings:
//   A: A[m=lane&15][k=quad*8+j]   B: B[k=quad*8+j][n=lane&15]
//   C: C[row=quad*4+r][col=lane&15]
// ---------------------------------------------------------------------------
__global__ __launch_bounds__(256) void attn(
    const __hip_bfloat16* __restrict__ qh, const __hip_bfloat16* __restrict__ kh,
    const __hip_bfloat16* __restrict__ vt, __hip_bfloat16* __restrict__ ctx)
{
    __shared__ __hip_bfloat16 Kt[64][72];        // [key][d]
    __shared__ __hip_bfloat16 Vt[64][72];        // [d][key]
    __shared__ __hip_bfloat16 Pl[4][16][72];     // per-wave P round-trip

    const int bh   = blockIdx.y;                 // b*H + h
    const int q0   = blockIdx.x * 64;
    const int tid  = threadIdx.x;
    const int wv   = tid >> 6;
    const int lane = tid & 63;
    const int l16  = lane & 15;
    const int quad = lane >> 4;
    const int b    = bh >> 4, h = bh & 15;

    // Q fragments for this wave's 16 rows (held in registers for whole loop)
    const __hip_bfloat16* __restrict__ qbase =
        qh + ((size_t)bh * S_ + q0 + wv * 16 + l16) * HD_;
    const shortx8 aq0 = *(const shortx8*)(qbase + quad * 8);
    const shortx8 aq1 = *(const shortx8*)(qbase + 32 + quad * 8);

    floatx4 O[4] = {};                           // 16 q-rows x 64 d (4 d-tiles)
    float m_i[4], l_i[4];
#pragma unroll
    for (int r = 0; r < 4; ++r) { m_i[r] = -1e30f; l_i[r] = 0.0f; }

    const __hip_bfloat16* __restrict__ kbase = kh + (size_t)bh * S_ * HD_;
    const __hip_bfloat16* __restrict__ vbase = vt + (size_t)bh * HD_ * S_;

    const int sr = tid >> 2;            // staging row 0..63
    const int sc = (tid & 3) * 16;      // staging col group (16 bf16)

    for (int kt = 0; kt < S_ / 64; ++kt) {
        // ---- stage K tile [key][d] and V^T tile [d][key] ----
        const __hip_bfloat16* kp = kbase + ((size_t)(kt * 64 + sr)) * HD_ + sc;
        uint4 kv0 = *(const uint4*)kp;
        uint4 kv1 = *(const uint4*)(kp + 8);
        const __hip_bfloat16* vp = vbase + (size_t)sr * S_ + kt * 64 + sc;
        uint4 vv0 = *(const uint4*)vp;
        uint4 vv1 = *(const uint4*)(vp + 8);
        *(uint4*)&Kt[sr][sc]     = kv0;
        *(uint4*)&Kt[sr][sc + 8] = kv1;
        *(uint4*)&Vt[sr][sc]     = vv0;
        *(uint4*)&Vt[sr][sc + 8] = vv1;
        __syncthreads();

        // ---- QK^T: 16 q-rows x 64 keys ----
        floatx4 s4[4];
#pragma unroll
        for (int nt = 0; nt < 4; ++nt) {
            floatx4 c = {0.f, 0.f, 0.f, 0.f};
            const shortx8 b0 = *(const shortx8*)&Kt[nt * 16 + l16][quad * 8];
            const shortx8 b1 = *(const shortx8*)&Kt[nt * 16 + l16][32 + quad * 8];
            c = __builtin_amdgcn_mfma_f32_16x16x32_bf16(aq0, b0, c, 0, 0, 0);
            c = __builtin_amdgcn_mfma_f32_16x16x32_bf16(aq1, b1, c, 0, 0, 0);
            s4[nt] = c;
        }
#pragma unroll
        for (int nt = 0; nt < 4; ++nt)
#pragma unroll
            for (int r = 0; r < 4; ++r) s4[nt][r] *= 0.125f;   // scale = HD^-0.5

        // ---- online softmax (rows live across the 16 lanes of a quad) ----
        float mt[4];
#pragma unroll
        for (int r = 0; r < 4; ++r)
            mt[r] = fmaxf(fmaxf(s4[0][r], s4[1][r]), fmaxf(s4[2][r], s4[3][r]));
#pragma unroll
        for (int m = 1; m < 16; m <<= 1)
#pragma unroll
            for (int r = 0; r < 4; ++r) mt[r] = fmaxf(mt[r], __shfl_xor(mt[r], m));

        float pr[4][4], rs[4], alpha[4];
#pragma unroll
        for (int r = 0; r < 4; ++r) {
            const float mn = fmaxf(m_i[r], mt[r]);
            alpha[r] = __expf(m_i[r] - mn);
            m_i[r] = mn;
            float acc = 0.f;
#pragma unroll
            for (int nt = 0; nt < 4; ++nt) {
                const float p = __expf(s4[nt][r] - mn);
                pr[nt][r] = p;
                acc += p;
            }
            rs[r] = acc;
        }
#pragma unroll
        for (int m = 1; m < 16; m <<= 1)
#pragma unroll
            for (int r = 0; r < 4; ++r) rs[r] += __shfl_xor(rs[r], m);
#pragma unroll
        for (int r = 0; r < 4; ++r) l_i[r] = l_i[r] * alpha[r] + rs[r];
#pragma unroll
        for (int dt = 0; dt < 4; ++dt)
#pragma unroll
            for (int r = 0; r < 4; ++r) O[dt][r] *= alpha[r];

        // ---- P: C-layout -> A-layout via per-wave LDS round-trip ----
#pragma unroll
        for (int nt = 0; nt < 4; ++nt)
#pragma unroll
            for (int r = 0; r < 4; ++r)
                Pl[wv][quad * 4 + r][nt * 16 + l16] = __float2bfloat16(pr[nt][r]);
        asm volatile("s_waitcnt lgkmcnt(0)" ::: "memory");
        const shortx8 ap0 = *(const shortx8*)&Pl[wv][l16][quad * 8];
        const shortx8 ap1 = *(const shortx8*)&Pl[wv][l16][32 + quad * 8];

        // ---- PV: O += P(16x64) * V(64x64) ----
#pragma unroll
        for (int dt = 0; dt < 4; ++dt) {
            const shortx8 bv0 = *(const shortx8*)&Vt[dt * 16 + l16][quad * 8];
            const shortx8 bv1 = *(const shortx8*)&Vt[dt * 16 + l16][32 + quad * 8];
            O[dt] = __builtin_amdgcn_mfma_f32_16x16x32_bf16(ap0, bv0, O[dt], 0, 0, 0);
            O[dt] = __builtin_amdgcn_mfma_f32_16x16x32_bf16(ap1, bv1, O[dt], 0, 0, 0);
        }
        __syncthreads();
    }

    // ---- epilogue: normalize, store ctx [B,S,E] bf16 ----
#pragma unroll
    for (int dt = 0; dt < 4; ++dt)
#pragma unroll
        for (int r = 0; r < 4; ++r) {
            const float o = O[dt][r] / l_i[r];
            const int s = q0 + wv * 16 + quad * 4 + r;
            const int d = dt * 16 + l16;
            ctx[((size_t)(b * S_ + s)) * E_ + h * HD_ + d] = __float2bfloat16(o);
        }
}

// ---------------------------------------------------------------------------
// Kernel 5: out[m][n] = sum_k ctx[m][k] * W[n][k] + bias[n], fp32 out.
// 64x64 block tile, K-step 32, 4 waves each computing 16x64.
// ---------------------------------------------------------------------------
__global__ __launch_bounds__(256) void proj(
    const __hip_bfloat16* __restrict__ ctx, const __hip_bfloat16* __restrict__ wb,
    const float* __restrict__ bias, float* __restrict__ out)
{
    __shared__ __hip_bfloat16 As[64][40];   // [m][k], +8 pad
    __shared__ __hip_bfloat16 Bs[64][40];   // [n][k], +8 pad

    const int m0 = blockIdx.x * 64;
    const int n0 = blockIdx.y * 64;
    const int tid  = threadIdx.x;
    const int wv   = tid >> 6;
    const int lane = tid & 63;
    const int l16  = lane & 15;
    const int quad = lane >> 4;
    const int sr   = tid >> 2;          // 0..63
    const int sc8  = (tid & 3) * 8;     // 0,8,16,24

    floatx4 acc[4] = {};

    for (int k0 = 0; k0 < E_; k0 += 32) {
        const uint4 av = *(const uint4*)(ctx + (size_t)(m0 + sr) * E_ + k0 + sc8);
        const uint4 bv = *(const uint4*)(wb  + (size_t)(n0 + sr) * E_ + k0 + sc8);
        *(uint4*)&As[sr][sc8] = av;
        *(uint4*)&Bs[sr][sc8] = bv;
        __syncthreads();

        const shortx8 a = *(const shortx8*)&As[wv * 16 + l16][quad * 8];
#pragma unroll
        for (int nt = 0; nt < 4; ++nt) {
            const shortx8 bfr = *(const shortx8*)&Bs[nt * 16 + l16][quad * 8];
            acc[nt] = __builtin_amdgcn_mfma_f32_16x16x32_bf16(a, bfr, acc[nt], 0, 0, 0);
        }
        __syncthreads();
    }

#pragma unroll
    for (int nt = 0; nt < 4; ++nt)
#pragma unroll
        for (int r = 0; r < 4; ++r) {
            const int mrow = m0 + wv * 16 + quad * 4 + r;
            const int ncol = n0 + nt * 16 + l16;
            out[(size_t)mrow * E_ + ncol] = acc[nt][r] + bias[ncol];
        }
}

// ---------------------------------------------------------------------------
extern "C" void kernel_launch(void* const* d_in, const int* in_sizes, int n_in,
                              void* d_out, int out_size, void* d_ws, size_t ws_size,
                              hipStream_t stream)
{
    const float* q  = (const float*)d_in[0];
    const float* k  = (const float*)d_in[1];
    const float* v  = (const float*)d_in[2];
    const float* qw = (const float*)d_in[3];
    const float* kw = (const float*)d_in[4];
    const float* pw = (const float*)d_in[5];
    const float* pb = (const float*)d_in[6];
    float* out = (float*)d_out;

    char* ws = (char*)d_ws;
    const size_t SEG = (size_t)B_ * H_ * S_ * HD_ * 2;   // 16 MiB
    __hip_bfloat16* qh  = (__hip_bfloat16*)(ws);
    __hip_bfloat16* kh  = (__hip_bfloat16*)(ws + SEG);
    __hip_bfloat16* vt  = (__hip_bfloat16*)(ws + 2 * SEG);
    __hip_bfloat16* ctx = (__hip_bfloat16*)(ws + 3 * SEG);
    __hip_bfloat16* wbp = (__hip_bfloat16*)(ws + 4 * SEG);

    qk_prep<<<dim3(2 * B_ * S_ * H_ / 4), 256, 0, stream>>>(q, k, qw, kw, qh, kh);
    v_trans<<<dim3(S_ / 64, B_ * H_), 256, 0, stream>>>(v, vt);
    wconv<<<dim3(E_ * E_ / 4 / 256), 256, 0, stream>>>(pw, wbp);
    attn<<<dim3(S_ / 64, B_ * H_), 256, 0, stream>>>(qh, kh, vt, ctx);
    proj<<<dim3(B_ * S_ / 64, E_ / 64), 256, 0, stream>>>(ctx, wbp, pb, out);
}

// Round 3
// 330.218 us; speedup vs baseline: 1.3616x; 1.3616x over previous
//
#include <hip/hip_runtime.h>
#include <hip/hip_bf16.h>
#include <cstdint>

#define B_ 4
#define S_ 2048
#define E_ 1024
#define H_ 16
#define HD_ 64
#define EPS_ 1.1920928955078125e-07f

typedef __attribute__((ext_vector_type(8))) short shortx8;
typedef __attribute__((ext_vector_type(4))) float floatx4;

// exp2 constants: p = exp(s*0.125 - 8) = exp2(s*C1 + C2)
#define C1_ 0.18033688068389154f   // 0.125 * log2(e)
#define C2_ -11.541560363770059f   // -8 * log2(e)

// ---------------------------------------------------------------------------
// Kernel 1: fused RMSNorm + RoPE for q and k, cast to bf16, transpose to
// [B,H,S,HD]. One thread per 4 consecutive elements; one 16-lane quad per
// head-vector (HD=64). RoPE pairs are intra-thread (even dl).
// ---------------------------------------------------------------------------
__global__ __launch_bounds__(256) void qk_prep(
    const float* __restrict__ q, const float* __restrict__ k,
    const float* __restrict__ qw, const float* __restrict__ kw,
    __hip_bfloat16* __restrict__ qh, __hip_bfloat16* __restrict__ kh)
{
    const size_t PT = (size_t)B_ * S_ * E_ / 4;     // float4 groups per tensor
    size_t t = (size_t)blockIdx.x * 256 + threadIdx.x;
    const bool is_k = (t >= PT);
    if (is_k) t -= PT;

    const int row = (int)(t >> 8);        // (b,s) row: E/4 = 256 groups
    const int b   = row / S_;
    const int s   = row % S_;
    const int grp = (int)(t & 255);
    const int h   = grp >> 4;             // head
    const int dl  = (grp & 15) * 4;       // dim offset within head (mult of 4)

    const float* __restrict__ src = is_k ? k : q;
    const float* __restrict__ w   = is_k ? kw : qw;
    __hip_bfloat16* __restrict__ dst = is_k ? kh : qh;

    const float4 x  = ((const float4*)src)[t];
    const float4 wv = ((const float4*)w)[grp & 15];

    // RMS over the head-vector: 16 threads (one quad) hold it
    float ss = x.x * x.x + x.y * x.y + x.z * x.z + x.w * x.w;
#pragma unroll
    for (int m = 1; m < 16; m <<= 1) ss += __shfl_xor(ss, m);
    const float r = rsqrtf(ss * (1.0f / HD_) + EPS_);

    const float xn0 = x.x * r * wv.x;
    const float xn1 = x.y * r * wv.y;
    const float xn2 = x.z * r * wv.z;
    const float xn3 = x.w * r * wv.w;

    // RoPE: pairs (dl,dl+1) and (dl+2,dl+3); i = pair index
    const float L2I = 0.41524101186092029f;   // log2(10000)/32
    const int   i0  = dl >> 1;
    const float f0  = (float)s * exp2f(-(float)i0 * L2I);
    const float f1  = (float)s * exp2f(-(float)(i0 + 1) * L2I);
    const float c0 = cosf(f0), sn0 = sinf(f0);
    const float c1 = cosf(f1), sn1 = sinf(f1);

    __hip_bfloat16 pk[4];
    pk[0] = __float2bfloat16(xn0 * c0 - xn1 * sn0);
    pk[1] = __float2bfloat16(xn0 * sn0 + xn1 * c0);
    pk[2] = __float2bfloat16(xn2 * c1 - xn3 * sn1);
    pk[3] = __float2bfloat16(xn2 * sn1 + xn3 * c1);
    *(ushort4*)(dst + ((size_t)((b * H_ + h) * S_ + s)) * HD_ + dl) =
        *(const ushort4*)pk;
}

// ---------------------------------------------------------------------------
// Kernel 2: transpose V to [B,H,HD,S] bf16 via LDS 64x64 tile.
// ---------------------------------------------------------------------------
__global__ __launch_bounds__(256) void v_trans(
    const float* __restrict__ v, __hip_bfloat16* __restrict__ vt)
{
    __shared__ __hip_bfloat16 tile[64][72];

    const int bh = blockIdx.y;
    const int s0 = blockIdx.x * 64;
    const int b  = bh >> 4, h = bh & 15;
    const int t  = threadIdx.x;

    {
        const int sl = t >> 2;
        const int d0 = (t & 3) * 16;
        const float* __restrict__ src =
            v + ((size_t)(b * S_ + s0 + sl)) * E_ + h * HD_ + d0;
        float4 f0 = ((const float4*)src)[0];
        float4 f1 = ((const float4*)src)[1];
        float4 f2 = ((const float4*)src)[2];
        float4 f3 = ((const float4*)src)[3];
        float vals[16] = {f0.x,f0.y,f0.z,f0.w, f1.x,f1.y,f1.z,f1.w,
                          f2.x,f2.y,f2.z,f2.w, f3.x,f3.y,f3.z,f3.w};
#pragma unroll
        for (int j = 0; j < 16; ++j)
            tile[d0 + j][sl] = __float2bfloat16(vals[j]);
    }
    __syncthreads();
    {
        const int d  = t >> 2;
        const int sg = (t & 3) * 16;
        __hip_bfloat16* __restrict__ dst =
            vt + ((size_t)(bh * HD_ + d)) * S_ + s0 + sg;
        ((uint4*)dst)[0] = *(const uint4*)&tile[d][sg];
        ((uint4*)dst)[1] = *(const uint4*)&tile[d][sg + 8];
    }
}

// ---------------------------------------------------------------------------
// Kernel 3: proj_w fp32 -> bf16
// ---------------------------------------------------------------------------
__global__ __launch_bounds__(256) void wconv(
    const float* __restrict__ w, __hip_bfloat16* __restrict__ wb)
{
    const int i = blockIdx.x * 256 + threadIdx.x;
    float4 f = ((const float4*)w)[i];
    wb[4 * i + 0] = __float2bfloat16(f.x);
    wb[4 * i + 1] = __float2bfloat16(f.y);
    wb[4 * i + 2] = __float2bfloat16(f.z);
    wb[4 * i + 3] = __float2bfloat16(f.w);
}

// ---------------------------------------------------------------------------
// Kernel 4: flash attention, fixed-max softmax (|logit*scale| <= 8 by
// Cauchy-Schwarz after RMSNorm: ||q||=||k||=8, scale=1/8).
// Block = 4 waves; each wave owns 32 Q rows (two 16-row halves). BM=128.
// K tiles of 64. Row-sums l computed by MFMA via a ones-row d-tile in Vt.
// MFMA 16x16x32 bf16 layouts (m89/m91/m120 verified):
//   A[m=lane&15][k=quad*8+j]  B[k=quad*8+j][n=lane&15]  C[row=quad*4+r][col=lane&15]
// ---------------------------------------------------------------------------
__global__ __launch_bounds__(256) void attn(
    const __hip_bfloat16* __restrict__ qh, const __hip_bfloat16* __restrict__ kh,
    const __hip_bfloat16* __restrict__ vt, __hip_bfloat16* __restrict__ ctx)
{
    __shared__ __hip_bfloat16 Kt[64][72];        // [key][d]
    __shared__ __hip_bfloat16 Vt[80][72];        // [d][key]; rows 64..79: ones-tile
    __shared__ __hip_bfloat16 Pl[4][16][72];     // per-wave P round-trip

    const int bh   = blockIdx.y;
    const int q0   = blockIdx.x * 128;
    const int tid  = threadIdx.x;
    const int wv   = tid >> 6;
    const int lane = tid & 63;
    const int l16  = lane & 15;
    const int quad = lane >> 4;
    const int b    = bh >> 4, h = bh & 15;

    // init ones-tile rows of Vt (row 64 = 1.0, rows 65..79 = 0)
    for (int idx = tid; idx < 16 * 72; idx += 256) {
        const int rr = idx / 72, cc = idx % 72;
        Vt[64 + rr][cc] = (rr == 0) ? __float2bfloat16(1.0f)
                                    : __float2bfloat16(0.0f);
    }

    // Q fragments: two 16-row halves
    shortx8 aq[2][2];
#pragma unroll
    for (int mh = 0; mh < 2; ++mh) {
        const __hip_bfloat16* qbase =
            qh + ((size_t)bh * S_ + q0 + wv * 32 + mh * 16 + l16) * HD_;
        aq[mh][0] = *(const shortx8*)(qbase + quad * 8);
        aq[mh][1] = *(const shortx8*)(qbase + 32 + quad * 8);
    }

    floatx4 O[2][4] = {};     // [m-half][d-tile]
    floatx4 O5[2]   = {};     // row-sum accumulator (ones-tile)

    const __hip_bfloat16* __restrict__ kbase = kh + (size_t)bh * S_ * HD_;
    const __hip_bfloat16* __restrict__ vbase = vt + (size_t)bh * HD_ * S_;

    const int sr = tid >> 2;
    const int sc = (tid & 3) * 16;

    for (int kt = 0; kt < S_ / 64; ++kt) {
        const __hip_bfloat16* kp = kbase + ((size_t)(kt * 64 + sr)) * HD_ + sc;
        uint4 kv0 = *(const uint4*)kp;
        uint4 kv1 = *(const uint4*)(kp + 8);
        const __hip_bfloat16* vp = vbase + (size_t)sr * S_ + kt * 64 + sc;
        uint4 vv0 = *(const uint4*)vp;
        uint4 vv1 = *(const uint4*)(vp + 8);
        *(uint4*)&Kt[sr][sc]     = kv0;
        *(uint4*)&Kt[sr][sc + 8] = kv1;
        *(uint4*)&Vt[sr][sc]     = vv0;
        *(uint4*)&Vt[sr][sc + 8] = vv1;
        __syncthreads();

#pragma unroll
        for (int mh = 0; mh < 2; ++mh) {
            // ---- QK^T: 16 q-rows x 64 keys ----
            floatx4 s4[4];
#pragma unroll
            for (int nt = 0; nt < 4; ++nt) {
                floatx4 c = {0.f, 0.f, 0.f, 0.f};
                const shortx8 b0 = *(const shortx8*)&Kt[nt * 16 + l16][quad * 8];
                const shortx8 b1 = *(const shortx8*)&Kt[nt * 16 + l16][32 + quad * 8];
                c = __builtin_amdgcn_mfma_f32_16x16x32_bf16(aq[mh][0], b0, c, 0, 0, 0);
                c = __builtin_amdgcn_mfma_f32_16x16x32_bf16(aq[mh][1], b1, c, 0, 0, 0);
                s4[nt] = c;
            }

            // ---- fixed-max softmax numerator + pack to LDS ----
            asm volatile("s_waitcnt lgkmcnt(0)" ::: "memory");
#pragma unroll
            for (int nt = 0; nt < 4; ++nt)
#pragma unroll
                for (int r = 0; r < 4; ++r) {
                    const float p = exp2f(fmaf(s4[nt][r], C1_, C2_));
                    Pl[wv][quad * 4 + r][nt * 16 + l16] = __float2bfloat16(p);
                }
            asm volatile("s_waitcnt lgkmcnt(0)" ::: "memory");
            const shortx8 ap0 = *(const shortx8*)&Pl[wv][l16][quad * 8];
            const shortx8 ap1 = *(const shortx8*)&Pl[wv][l16][32 + quad * 8];

            // ---- PV: O += P(16x64) * V(64x64); l via ones-tile ----
#pragma unroll
            for (int dt = 0; dt < 4; ++dt) {
                const shortx8 bv0 = *(const shortx8*)&Vt[dt * 16 + l16][quad * 8];
                const shortx8 bv1 = *(const shortx8*)&Vt[dt * 16 + l16][32 + quad * 8];
                O[mh][dt] = __builtin_amdgcn_mfma_f32_16x16x32_bf16(ap0, bv0, O[mh][dt], 0, 0, 0);
                O[mh][dt] = __builtin_amdgcn_mfma_f32_16x16x32_bf16(ap1, bv1, O[mh][dt], 0, 0, 0);
            }
            {
                const shortx8 bo0 = *(const shortx8*)&Vt[64 + l16][quad * 8];
                const shortx8 bo1 = *(const shortx8*)&Vt[64 + l16][32 + quad * 8];
                O5[mh] = __builtin_amdgcn_mfma_f32_16x16x32_bf16(ap0, bo0, O5[mh], 0, 0, 0);
                O5[mh] = __builtin_amdgcn_mfma_f32_16x16x32_bf16(ap1, bo1, O5[mh], 0, 0, 0);
            }
        }
        __syncthreads();
    }

    // ---- epilogue: normalize (l sits at col 0 of ones-tile = lane quad*16) ----
#pragma unroll
    for (int mh = 0; mh < 2; ++mh)
#pragma unroll
        for (int r = 0; r < 4; ++r) {
            const float lv  = __shfl(O5[mh][r], quad << 4);
            const float inv = 1.0f / lv;
            const int s = q0 + wv * 32 + mh * 16 + quad * 4 + r;
#pragma unroll
            for (int dt = 0; dt < 4; ++dt) {
                const int d = dt * 16 + l16;
                ctx[((size_t)(b * S_ + s)) * E_ + h * HD_ + d] =
                    __float2bfloat16(O[mh][dt][r] * inv);
            }
        }
}

// ---------------------------------------------------------------------------
// Kernel 5: out[m][n] = sum_k ctx[m][k] * W[n][k] + bias[n], fp32 out.
// ---------------------------------------------------------------------------
__global__ __launch_bounds__(256) void proj(
    const __hip_bfloat16* __restrict__ ctx, const __hip_bfloat16* __restrict__ wb,
    const float* __restrict__ bias, float* __restrict__ out)
{
    __shared__ __hip_bfloat16 As[64][40];
    __shared__ __hip_bfloat16 Bs[64][40];

    const int m0 = blockIdx.x * 64;
    const int n0 = blockIdx.y * 64;
    const int tid  = threadIdx.x;
    const int wv   = tid >> 6;
    const int lane = tid & 63;
    const int l16  = lane & 15;
    const int quad = lane >> 4;
    const int sr   = tid >> 2;
    const int sc8  = (tid & 3) * 8;

    floatx4 acc[4] = {};

    for (int k0 = 0; k0 < E_; k0 += 32) {
        const uint4 av = *(const uint4*)(ctx + (size_t)(m0 + sr) * E_ + k0 + sc8);
        const uint4 bv = *(const uint4*)(wb  + (size_t)(n0 + sr) * E_ + k0 + sc8);
        *(uint4*)&As[sr][sc8] = av;
        *(uint4*)&Bs[sr][sc8] = bv;
        __syncthreads();

        const shortx8 a = *(const shortx8*)&As[wv * 16 + l16][quad * 8];
#pragma unroll
        for (int nt = 0; nt < 4; ++nt) {
            const shortx8 bfr = *(const shortx8*)&Bs[nt * 16 + l16][quad * 8];
            acc[nt] = __builtin_amdgcn_mfma_f32_16x16x32_bf16(a, bfr, acc[nt], 0, 0, 0);
        }
        __syncthreads();
    }

#pragma unroll
    for (int nt = 0; nt < 4; ++nt)
#pragma unroll
        for (int r = 0; r < 4; ++r) {
            const int mrow = m0 + wv * 16 + quad * 4 + r;
            const int ncol = n0 + nt * 16 + l16;
            out[(size_t)mrow * E_ + ncol] = acc[nt][r] + bias[ncol];
        }
}

// ---------------------------------------------------------------------------
extern "C" void kernel_launch(void* const* d_in, const int* in_sizes, int n_in,
                              void* d_out, int out_size, void* d_ws, size_t ws_size,
                              hipStream_t stream)
{
    const float* q  = (const float*)d_in[0];
    const float* k  = (const float*)d_in[1];
    const float* v  = (const float*)d_in[2];
    const float* qw = (const float*)d_in[3];
    const float* kw = (const float*)d_in[4];
    const float* pw = (const float*)d_in[5];
    const float* pb = (const float*)d_in[6];
    float* out = (float*)d_out;

    char* ws = (char*)d_ws;
    const size_t SEG = (size_t)B_ * H_ * S_ * HD_ * 2;   // 16 MiB
    __hip_bfloat16* qh  = (__hip_bfloat16*)(ws);
    __hip_bfloat16* kh  = (__hip_bfloat16*)(ws + SEG);
    __hip_bfloat16* vt  = (__hip_bfloat16*)(ws + 2 * SEG);
    __hip_bfloat16* ctx = (__hip_bfloat16*)(ws + 3 * SEG);
    __hip_bfloat16* wbp = (__hip_bfloat16*)(ws + 4 * SEG);

    qk_prep<<<dim3(2 * B_ * S_ * E_ / 4 / 256), 256, 0, stream>>>(q, k, qw, kw, qh, kh);
    v_trans<<<dim3(S_ / 64, B_ * H_), 256, 0, stream>>>(v, vt);
    wconv<<<dim3(E_ * E_ / 4 / 256), 256, 0, stream>>>(pw, wbp);
    attn<<<dim3(S_ / 128, B_ * H_), 256, 0, stream>>>(qh, kh, vt, ctx);
    proj<<<dim3(B_ * S_ / 64, E_ / 64), 256, 0, stream>>>(ctx, wbp, pb, out);
}